// Round 1
// baseline (100.267 us; speedup 1.0000x reference)
//
#include <hip/hip_runtime.h>

#define NN 2048
#define DD 128
#define KK 16

// One wave (64 threads) per output row (b,i).
__global__ __launch_bounds__(64) void rc_topk_kernel(
    const float* __restrict__ s,        // [B,N,D]
    const float* __restrict__ noise,    // [B,N,N]
    const int*   __restrict__ adj,      // [B,N,N]
    const int*   __restrict__ active,   // [B,N]
    const int*   __restrict__ act,      // [B,N]
    float* __restrict__ ctx,            // [B,N,D]
    float* __restrict__ gate,           // [B,N,N]
    float* __restrict__ w)              // [B,N,N]
{
    __shared__ float sc[NN];
    __shared__ int   sel[KK];

    const int lane = threadIdx.x;          // 0..63
    const int row  = blockIdx.x;           // b*N + i
    const int b    = row >> 11;            // /2048
    const long long rowoff = (long long)row * NN;

    const int actv = act[row];
    if (actv == 0) {
        // Entire row is zero: gate, w, ctx. No noise/adj reads.
        const float4 z4 = make_float4(0.f, 0.f, 0.f, 0.f);
        #pragma unroll
        for (int t = 0; t < 8; ++t) {
            const int j = t * 256 + lane * 4;
            *(float4*)&gate[rowoff + j] = z4;
            *(float4*)&w[rowoff + j]    = z4;
        }
        *(float2*)&ctx[(long long)row * DD + lane * 2] = make_float2(0.f, 0.f);
        return;
    }

    // ---- Load + score + per-lane running max (tie-break: smallest j) ----
    float bv = -2.0f; int bj = 1 << 30;
    #pragma unroll
    for (int t = 0; t < 8; ++t) {
        const int j = t * 256 + lane * 4;
        const float4 nz = *(const float4*)&noise[rowoff + j];
        const int4   ad = *(const int4*)&adj[rowoff + j];
        const int4   am = *(const int4*)&active[b * NN + j];
        const float v0 = (ad.x > 0 && am.x > 0) ? nz.x : -1.0f;
        const float v1 = (ad.y > 0 && am.y > 0) ? nz.y : -1.0f;
        const float v2 = (ad.z > 0 && am.z > 0) ? nz.z : -1.0f;
        const float v3 = (ad.w > 0 && am.w > 0) ? nz.w : -1.0f;
        *(float4*)&sc[j] = make_float4(v0, v1, v2, v3);
        // ascending-j scan with strict '>' keeps smallest index on ties
        if (v0 > bv) { bv = v0; bj = j;     }
        if (v1 > bv) { bv = v1; bj = j + 1; }
        if (v2 > bv) { bv = v2; bj = j + 2; }
        if (v3 > bv) { bv = v3; bj = j + 3; }
    }

    // ---- 16x extraction: wave butterfly max (value desc, index asc) ----
    int cnt = 0;
    for (int k = 0; k < KK; ++k) {
        float rv = bv; int rj = bj;
        #pragma unroll
        for (int off = 32; off > 0; off >>= 1) {
            const float ov = __shfl_xor(rv, off, 64);
            const int   oj = __shfl_xor(rj, off, 64);
            if (ov > rv || (ov == rv && oj < rj)) { rv = ov; rj = oj; }
        }
        if (rv < 0.0f) break;              // uniform: no valid candidates left
        if (lane == 0) sel[k] = rj;
        ++cnt;
        if (bj == rj) {                    // only the owning lane matches
            sc[rj] = -2.0f;                // consume (lane-private slot)
            bv = -2.0f; bj = 1 << 30;
            #pragma unroll
            for (int t = 0; t < 8; ++t) {
                const int j = t * 256 + lane * 4;
                const float4 q = *(const float4*)&sc[j];
                if (q.x > bv) { bv = q.x; bj = j;     }
                if (q.y > bv) { bv = q.y; bj = j + 1; }
                if (q.z > bv) { bv = q.z; bj = j + 2; }
                if (q.w > bv) { bv = q.w; bj = j + 3; }
            }
        }
    }

    __syncthreads();                        // sel[] visible wave-wide
    const float inv = 1.0f / (float)(cnt > 1 ? cnt : 1);

    // ---- Rebuild LDS row as gate row ----
    const float4 z4 = make_float4(0.f, 0.f, 0.f, 0.f);
    #pragma unroll
    for (int t = 0; t < 8; ++t) *(float4*)&sc[t * 256 + lane * 4] = z4;
    __syncthreads();
    if (lane < cnt) sc[sel[lane]] = 1.0f;   // distinct indices, no collisions
    __syncthreads();

    // ---- Stream gate and w out, coalesced ----
    #pragma unroll
    for (int t = 0; t < 8; ++t) {
        const int j = t * 256 + lane * 4;
        const float4 g = *(const float4*)&sc[j];
        *(float4*)&gate[rowoff + j] = g;
        *(float4*)&w[rowoff + j] = make_float4(g.x * inv, g.y * inv, g.z * inv, g.w * inv);
    }

    // ---- ctx = (1/cnt) * sum of selected s rows ----
    float2 acc = make_float2(0.f, 0.f);
    for (int k = 0; k < cnt; ++k) {
        const int j = sel[k];               // wave-uniform LDS read
        const float2 sv = *(const float2*)&s[((long long)(b * NN + j)) * DD + lane * 2];
        acc.x += sv.x; acc.y += sv.y;
    }
    *(float2*)&ctx[(long long)row * DD + lane * 2] = make_float2(acc.x * inv, acc.y * inv);
}

extern "C" void kernel_launch(void* const* d_in, const int* in_sizes, int n_in,
                              void* d_out, int out_size, void* d_ws, size_t ws_size,
                              hipStream_t stream) {
    const float* s      = (const float*)d_in[0];
    const float* noise  = (const float*)d_in[1];
    const int*   adj    = (const int*)d_in[2];
    const int*   active = (const int*)d_in[3];
    const int*   act    = (const int*)d_in[4];

    const int B = in_sizes[3] / NN;                  // active_mask is [B,N]
    const long long ctxN  = (long long)B * NN * DD;
    const long long gateN = (long long)B * NN * NN;

    float* ctx  = (float*)d_out;
    float* gate = ctx + ctxN;
    float* wout = gate + gateN;

    rc_topk_kernel<<<B * NN, 64, 0, stream>>>(s, noise, adj, active, act, ctx, gate, wout);
}

// Round 3
// 74.878 us; speedup vs baseline: 1.3391x; 1.3391x over previous
//
#include <hip/hip_runtime.h>

#define NN 2048
#define DD 128
#define KK 16
#define DIRTY 0xFFFFFFFFFFFFFFFFull

typedef float f4 __attribute__((ext_vector_type(4)));   // native vec for nontemporal

// Sortable key: (value desc, index asc). Valid scores are uniform [0,1) -> bits in
// [0,0x3F800000); +1 keeps key>0 so 0 can mean "no candidate". Low 11 bits = 2047-j
// so larger key == smaller index at equal value (matches jax top_k tie-break).
__device__ __forceinline__ unsigned long long packkey(float v, int j) {
    unsigned long long k = ((unsigned long long)(__float_as_uint(v) + 1u) << 11)
                         | (unsigned int)(2047 - j);
    return (v >= 0.0f) ? k : 0ull;
}

// One wave (64 threads) per output row (b,i).
__global__ __launch_bounds__(64) void rc_topk_kernel(
    const float* __restrict__ s,        // [B,N,D]
    const float* __restrict__ noise,    // [B,N,N]
    const int*   __restrict__ adj,      // [B,N,N]
    const int*   __restrict__ active,   // [B,N]
    const int*   __restrict__ act,      // [B,N]
    float* __restrict__ ctx,            // [B,N,D]
    float* __restrict__ gate,           // [B,N,N]
    float* __restrict__ w)              // [B,N,N]
{
    __shared__ float sc[NN];

    const int lane = threadIdx.x;          // 0..63
    const int row  = blockIdx.x;           // b*N + i
    const int b    = row >> 11;            // /2048
    const long long rowoff = (long long)row * NN;

    if (act[row] == 0) {
        const f4 z4 = (f4)0.0f;
        #pragma unroll
        for (int t = 0; t < 8; ++t) {
            const int j = t * 256 + lane * 4;
            __builtin_nontemporal_store(z4, (f4*)&gate[rowoff + j]);
            __builtin_nontemporal_store(z4, (f4*)&w[rowoff + j]);
        }
        *(float2*)&ctx[(long long)row * DD + lane * 2] = make_float2(0.f, 0.f);
        return;
    }

    // ---- Load + score + per-lane top-2 (ascending j, strict '>' => min index on ties)
    float b1v = -4.0f, b2v = -4.0f; int b1j = 0, b2j = 0;
    #pragma unroll
    for (int t = 0; t < 8; ++t) {
        const int j = t * 256 + lane * 4;
        const float4 nz = *(const float4*)&noise[rowoff + j];
        const int4   ad = *(const int4*)&adj[rowoff + j];
        const int4   am = *(const int4*)&active[b * NN + j];
        const float v0 = (ad.x > 0 && am.x > 0) ? nz.x : -1.0f;
        const float v1 = (ad.y > 0 && am.y > 0) ? nz.y : -1.0f;
        const float v2 = (ad.z > 0 && am.z > 0) ? nz.z : -1.0f;
        const float v3 = (ad.w > 0 && am.w > 0) ? nz.w : -1.0f;
        *(float4*)&sc[j] = make_float4(v0, v1, v2, v3);
        if (v0 > b1v) { b2v = b1v; b2j = b1j; b1v = v0; b1j = j;     }
        else if (v0 > b2v) { b2v = v0; b2j = j;     }
        if (v1 > b1v) { b2v = b1v; b2j = b1j; b1v = v1; b1j = j + 1; }
        else if (v1 > b2v) { b2v = v1; b2j = j + 1; }
        if (v2 > b1v) { b2v = b1v; b2j = b1j; b1v = v2; b1j = j + 2; }
        else if (v2 > b2v) { b2v = v2; b2j = j + 2; }
        if (v3 > b1v) { b2v = b1v; b2j = b1j; b1v = v3; b1j = j + 3; }
        else if (v3 > b2v) { b2v = v3; b2j = j + 3; }
    }
    unsigned long long k1 = packkey(b1v, b1j);
    unsigned long long k2 = packkey(b2v, b2j);   // never DIRTY here

    // ---- 16x extraction: u64 butterfly max; rescan only on a lane's 2nd win ----
    int cnt = 0, myj = -1;
    float2 acc  = make_float2(0.f, 0.f);
    float2 pend = make_float2(0.f, 0.f);
    for (int k = 0; k < KK; ++k) {
        unsigned long long rk = k1;
        #pragma unroll
        for (int off = 32; off > 0; off >>= 1) {
            const unsigned long long o = __shfl_xor(rk, off, 64);
            if (o > rk) rk = o;
        }
        if (rk == 0ull) break;             // no valid candidates left
        acc.x += pend.x; acc.y += pend.y;  // consume previous iteration's s-load
        const int rj = 2047 - (int)((unsigned int)rk & 0x7FFu);
        pend = *(const float2*)&s[((long long)(b * NN + rj)) * DD + lane * 2];
        if (lane == k) myj = rj;
        ++cnt;
        if (k1 == rk) {                    // unique owner (index embedded in key)
            sc[rj] = -2.0f;                // consumed
            if (k2 != DIRTY) { k1 = k2; k2 = DIRTY; }
            else {                         // second win: full rescan of remaining
                float c1v = -4.0f, c2v = -4.0f; int c1j = 0, c2j = 0;
                #pragma unroll
                for (int t = 0; t < 8; ++t) {
                    const int j = t * 256 + lane * 4;
                    const float4 q = *(const float4*)&sc[j];
                    if (q.x > c1v) { c2v = c1v; c2j = c1j; c1v = q.x; c1j = j;     }
                    else if (q.x > c2v) { c2v = q.x; c2j = j;     }
                    if (q.y > c1v) { c2v = c1v; c2j = c1j; c1v = q.y; c1j = j + 1; }
                    else if (q.y > c2v) { c2v = q.y; c2j = j + 1; }
                    if (q.z > c1v) { c2v = c1v; c2j = c1j; c1v = q.z; c1j = j + 2; }
                    else if (q.z > c2v) { c2v = q.z; c2j = j + 2; }
                    if (q.w > c1v) { c2v = c1v; c2j = c1j; c1v = q.w; c1j = j + 3; }
                    else if (q.w > c2v) { c2v = q.w; c2j = j + 3; }
                }
                k1 = packkey(c1v, c1j);
                k2 = packkey(c2v, c2j);    // genuine (may be 0 = lane exhausted)
            }
        }
    }
    acc.x += pend.x; acc.y += pend.y;      // last pending row

    __syncthreads();
    const float inv = 1.0f / (float)(cnt > 1 ? cnt : 1);

    // ---- Rebuild LDS row as gate row ----
    const float4 z4h = make_float4(0.f, 0.f, 0.f, 0.f);
    #pragma unroll
    for (int t = 0; t < 8; ++t) *(float4*)&sc[t * 256 + lane * 4] = z4h;
    __syncthreads();
    if (lane < cnt) sc[myj] = 1.0f;        // distinct indices, no collisions
    __syncthreads();

    // ---- Stream gate and w out, coalesced, nontemporal ----
    #pragma unroll
    for (int t = 0; t < 8; ++t) {
        const int j = t * 256 + lane * 4;
        const f4 g = *(const f4*)&sc[j];
        __builtin_nontemporal_store(g, (f4*)&gate[rowoff + j]);
        const f4 wv = g * inv;
        __builtin_nontemporal_store(wv, (f4*)&w[rowoff + j]);
    }

    // ---- ctx ----
    *(float2*)&ctx[(long long)row * DD + lane * 2] = make_float2(acc.x * inv, acc.y * inv);
}

extern "C" void kernel_launch(void* const* d_in, const int* in_sizes, int n_in,
                              void* d_out, int out_size, void* d_ws, size_t ws_size,
                              hipStream_t stream) {
    const float* s      = (const float*)d_in[0];
    const float* noise  = (const float*)d_in[1];
    const int*   adj    = (const int*)d_in[2];
    const int*   active = (const int*)d_in[3];
    const int*   act    = (const int*)d_in[4];

    const int B = in_sizes[3] / NN;                  // active_mask is [B,N]
    const long long ctxN  = (long long)B * NN * DD;
    const long long gateN = (long long)B * NN * NN;

    float* ctxp = (float*)d_out;
    float* gatep = ctxp + ctxN;
    float* wp = gatep + gateN;

    rc_topk_kernel<<<B * NN, 64, 0, stream>>>(s, noise, adj, active, act, ctxp, gatep, wp);
}